// Round 1
// baseline (1321.520 us; speedup 1.0000x reference)
//
#include <hip/hip_runtime.h>
#include <hip/hip_fp16.h>
#include <math.h>

#define NT      1024
#define NPIX    16384
#define NSLICES 8
#define NMODES  4
#define OBJW    512
#define LSTR    136        // padded major stride (half2 units): 136%32=8

// ---- complex helpers -------------------------------------------------------
__device__ __forceinline__ float2 cmul(float2 a, float2 b) {
    return make_float2(fmaf(a.x, b.x, -a.y * b.y), fmaf(a.x, b.y, a.y * b.x));
}

// 4-bit reversal (constexpr -> folds to literals in unrolled loops)
__host__ __device__ constexpr int BR4(int p) {
    return ((p & 1) << 3) | ((p & 2) << 1) | ((p & 4) >> 1) | ((p & 8) >> 3);
}
__host__ __device__ constexpr int BR3(int c) {
    return ((c & 1) << 2) | (c & 2) | ((c & 4) >> 2);
}

// ---- lane exchange primitives ---------------------------------------------
// xor1/xor2 stay inside a quad -> DPP quad_perm (full-rate VALU, no LDS pipe).
// xor4 has no DPP control -> ds_swizzle bit-mode (no index operand, cheaper
// than the ds_bpermute that __shfl_xor lowers to).
__device__ __forceinline__ float xor1f(float x) {
    int i = __float_as_int(x);
    return __int_as_float(__builtin_amdgcn_update_dpp(i, i, 0xB1, 0xF, 0xF, false)); // quad_perm [1,0,3,2]
}
__device__ __forceinline__ float xor2f(float x) {
    int i = __float_as_int(x);
    return __int_as_float(__builtin_amdgcn_update_dpp(i, i, 0x4E, 0xF, 0xF, false)); // quad_perm [2,3,0,1]
}
__device__ __forceinline__ float xor4f(float x) {
    return __int_as_float(__builtin_amdgcn_ds_swizzle(__float_as_int(x), 0x101F)); // xor4, and=0x1F
}

// W16^k tables
__device__ __constant__ float TWC16[8] = {
    1.0f, 0.923879533f, 0.707106781f, 0.382683432f,
    0.0f, -0.382683432f, -0.707106781f, -0.923879533f };
__device__ __constant__ float TWS16[8] = {
    0.0f, 0.382683432f, 0.707106781f, 0.923879533f,
    1.0f, 0.923879533f, 0.707106781f, 0.382683432f };
// cross-8 stage-A twiddle fA(c) = (c<4) ? 1 : W8^(c-4)
__device__ __constant__ float FA_RE[8] = {1,1,1,1, 1.0f,  0.707106781f,  0.0f, -0.707106781f};
__device__ __constant__ float FA_IM[8] = {0,0,0,0, 0.0f, -0.707106781f, -1.0f, -0.707106781f};

// ---- local 16-point FFT in registers ---------------------------------------
__device__ __forceinline__ void fft16_fwd(float2 v[16]) {
    #pragma unroll
    for (int s = 8; s >= 1; s >>= 1) {
        #pragma unroll
        for (int q = 0; q < 16; q += 2 * s) {
            #pragma unroll
            for (int j = 0; j < s; j++) {
                const int tw = j * (8 / s);
                float2 u = v[q + j], w = v[q + j + s];
                v[q + j] = make_float2(u.x + w.x, u.y + w.y);
                float dx = u.x - w.x, dy = u.y - w.y;
                v[q + j + s] = make_float2(fmaf(dx, TWC16[tw],  dy * TWS16[tw]),
                                           fmaf(dy, TWC16[tw], -dx * TWS16[tw]));
            }
        }
    }
}
__device__ __forceinline__ void fft16_inv(float2 v[16]) {
    #pragma unroll
    for (int s = 1; s <= 8; s <<= 1) {
        #pragma unroll
        for (int q = 0; q < 16; q += 2 * s) {
            #pragma unroll
            for (int j = 0; j < s; j++) {
                const int tw = j * (8 / s);
                float2 u = v[q + j], w = v[q + j + s];
                float2 tv = make_float2(fmaf(w.x, TWC16[tw], -w.y * TWS16[tw]),
                                        fmaf(w.y, TWC16[tw],  w.x * TWS16[tw]));
                v[q + j]     = make_float2(u.x + tv.x, u.y + tv.y);
                v[q + j + s] = make_float2(u.x - tv.x, u.y - tv.y);
            }
        }
    }
}

// ---- cross-thread DFT8 over sub-index c (xor 4,2,1) ------------------------
// fwd: natural in, output at thread br3(c). inv: br3-in, natural out (unnorm).
__device__ __forceinline__ void cross8_fwd(float2 v[16], int c, float2 fA) {
    const float sA = (c < 4) ? 1.0f : -1.0f;
    const float sB = (c & 2) ? -1.0f : 1.0f;
    const float sC = (c & 1) ? -1.0f : 1.0f;
    const bool rot3 = ((c & 3) == 3);
    #pragma unroll
    for (int p = 0; p < 16; p++) {
        float ox = xor4f(v[p].x), oy = xor4f(v[p].y);
        float ax = fmaf(sA, v[p].x, ox), ay = fmaf(sA, v[p].y, oy);
        float bx = fmaf(ax, fA.x, -ay * fA.y);
        float by = fmaf(ax, fA.y,  ay * fA.x);
        ox = xor2f(bx); oy = xor2f(by);
        float nx = fmaf(sB, bx, ox), ny = fmaf(sB, by, oy);
        float rx = rot3 ?  ny : nx;
        float ry = rot3 ? -nx : ny;
        ox = xor1f(rx); oy = xor1f(ry);
        v[p].x = fmaf(sC, rx, ox); v[p].y = fmaf(sC, ry, oy);
    }
}
__device__ __forceinline__ void cross8_inv(float2 v[16], int c, float2 fA) {
    const float sA = (c < 4) ? 1.0f : -1.0f;
    const float sB = (c & 2) ? -1.0f : 1.0f;
    const float sC = (c & 1) ? -1.0f : 1.0f;
    const bool rot3 = ((c & 3) == 3);
    #pragma unroll
    for (int p = 0; p < 16; p++) {
        float ox = xor1f(v[p].x), oy = xor1f(v[p].y);
        float nx = fmaf(sC, v[p].x, ox), ny = fmaf(sC, v[p].y, oy);
        float rx = rot3 ? -ny : nx;
        float ry = rot3 ?  nx : ny;
        ox = xor2f(rx); oy = xor2f(ry);
        float bx = fmaf(sB, rx, ox), by = fmaf(sB, ry, oy);
        float ax = fmaf(bx, fA.x,  by * fA.y);
        float ay = fmaf(by, fA.x, -bx * fA.y);
        ox = xor4f(ax); oy = xor4f(ay);
        v[p].x = fmaf(sA, ax, ox); v[p].y = fmaf(sA, ay, oy);
    }
}

// ---- pass A (local-first): input reg i = elem c+8i; out reg p = BR4(p)+16rc
// tA[8p+c] = W128^(c*BR4(p))  (broadcast-read, conflict-free)
__device__ __forceinline__ void pass_A_fwd(float2 v[16], int c, float2 fA,
                                           const float2* tA) {
    fft16_fwd(v);
    #pragma unroll
    for (int p = 0; p < 16; p++) v[p] = cmul(v[p], tA[8 * p + c]);
    cross8_fwd(v, c, fA);
}
__device__ __forceinline__ void pass_A_inv(float2 v[16], int c, float2 fA,
                                           const float2* tA) {
    cross8_inv(v, c, fA);
    #pragma unroll
    for (int p = 0; p < 16; p++) {
        float2 w = tA[8 * p + c];
        v[p] = cmul(v[p], make_float2(w.x, -w.y));
    }
    fft16_inv(v);
}

// ---- pass B (cross-first): input reg i = elem i+16c; out: thread holds
// k1=br3(c) (low 3 bits of k), reg p holds k2=BR4(p) (k = k1 + 8*k2).
// tB[8i+c] = W128^(i*br3(c))
__device__ __forceinline__ void pass_B_fwd(float2 v[16], int c, float2 fA,
                                           const float2* tB) {
    cross8_fwd(v, c, fA);
    #pragma unroll
    for (int i = 0; i < 16; i++) v[i] = cmul(v[i], tB[8 * i + c]);
    fft16_fwd(v);
}
__device__ __forceinline__ void pass_B_inv(float2 v[16], int c, float2 fA,
                                           const float2* tB) {
    fft16_inv(v);
    #pragma unroll
    for (int i = 0; i < 16; i++) {
        float2 w = tB[8 * i + c];
        v[i] = cmul(v[i], make_float2(w.x, -w.y));
    }
    cross8_inv(v, c, fA);
}

// ---- main kernel: one block per position; 2 blocks/CU (72.7KB LDS) ---------
// Transpose buffer in fp16 (__half2) with analytically conflict-free layout:
// addr(maj,min) = maj*136 + (rho(min) ^ (maj>>4)), rho = 7-bit rotl-3.
// All 4 transpose phases: 32 distinct banks, 2 lanes/bank (free floor).
__global__ void
__attribute__((amdgpu_flat_work_group_size(1024, 1024)))
multislice_kernel(const float* __restrict__ probe_re,
                  const float* __restrict__ probe_im,
                  const float* __restrict__ obj_re,
                  const float* __restrict__ obj_im,
                  const int*   __restrict__ positions,
                  float*       __restrict__ out)
{
    __shared__ __half2 LTH[128 * LSTR];   // 69632 B transpose buffer (fp16)
    __shared__ float2  tA[128];           // pass-A twiddle [8p+c]
    __shared__ float2  tB[128];           // pass-B twiddle [8i+c]
    __shared__ float2  pytp[128];         // prop y-factor/16384, kh=br3(c)+8BR4(p)

    const int t  = threadIdx.x;
    const int g  = t >> 3;                      // row (R) / col (C) index
    const int c  = t & 7;
    const int rc = BR3(c);
    const int gh = g >> 4;                      // sigma(g)
    const int rho_g = ((g & 15) << 3) | gh;     // rho(g)
    const int n  = blockIdx.x;
    const int Y0 = positions[2 * n];
    const int X0 = positions[2 * n + 1];

    if (t < 128) {
        int p_ = t >> 3, c_ = t & 7;
        float angA = -2.0f * 3.14159265358979323846f
                     * (float)(c_ * BR4(p_)) / 128.0f;
        float s, cc; __sincosf(angA, &s, &cc);
        tA[t] = make_float2(cc, s);
        float angB = -2.0f * 3.14159265358979323846f
                     * (float)(p_ * BR3(c_)) / 128.0f;
        __sincosf(angB, &s, &cc);
        tB[t] = make_float2(cc, s);
        int kh = BR3(c_) + 8 * BR4(p_);
        float fy = (float)(kh < 64 ? kh : kh - 128) * (1.0f / 25.6f);
        float ph = -0.15707963267948966f * fy * fy;
        float ps, pcs; __sincosf(ph, &ps, &pcs);
        pytp[t] = make_float2(pcs * (1.0f / 16384.0f), ps * (1.0f / 16384.0f));
    }
    const float2 fA = make_float2(FA_RE[c], FA_IM[c]);
    float fx = (float)(g < 64 ? g : g - 128) * (1.0f / 25.6f);
    float phx = -0.15707963267948966f * fx * fx;
    float pxs, pxc; __sincosf(phx, &pxs, &pxc);
    const float2 px = make_float2(pxc, pxs);
    __syncthreads();

    const long long base = (long long)n * NPIX;
    // precomputed transpose address bases
    const int a1w = rho_g ^ rc;        // T1-write minor (const per thread)
    const int a1r = g * LSTR + (c ^ gh);           // + 8i
    const int a2w = rho_g ^ c;         // T2-write minor
    const int a2r = g * LSTR + (rc ^ gh);          // + 8*BR4(p)

    float2 v[16];

    for (int m = 0; m < NMODES; m++) {
        __syncthreads();   // protect LTH reuse across modes
        #pragma unroll
        for (int i = 0; i < 16; i++) {           // ex = probe[m]*patch(slice0)
            int w  = c + 8 * i;
            int pi = m * NPIX + g * 128 + w;
            float2 pr = make_float2(probe_re[pi], probe_im[pi]);
            int oi = (Y0 + g) * OBJW + X0 + w;
            float2 ob = make_float2(obj_re[oi], obj_im[oi]);
            v[i] = cmul(pr, ob);
        }

        for (int s = 1; s < NSLICES; s++) {
            pass_A_fwd(v, c, fA, tA);            // Fw: reg p -> kw=BR4(p)+16rc
            #pragma unroll                       // T1 write [kw][r=g]
            for (int p = 0; p < 16; p++) {
                int kw = BR4(p) + 16 * rc;
                LTH[kw * LSTR + a1w] = __float22half2_rn(v[p]);
            }
            __syncthreads();
            #pragma unroll                       // T1 read -> C: reg i = row i+16c
            for (int i = 0; i < 16; i++)
                v[i] = __half22float2(LTH[a1r + 8 * i]);
            __syncthreads();
            pass_B_fwd(v, c, fA, tB);            // Fh: kh = br3(c)+8*BR4(p)
            #pragma unroll                       // * prop
            for (int p = 0; p < 16; p++) {
                float2 pp = cmul(pytp[8 * p + c], px);
                v[p] = cmul(v[p], pp);
            }
            pass_B_inv(v, c, fA, tB);            // iFh: reg i = row i+16c
            #pragma unroll                       // T2 write [r=i+16c][g]
            for (int i = 0; i < 16; i++)
                LTH[(i + 16 * c) * LSTR + a2w] = __float22half2_rn(v[i]);
            __syncthreads();
            #pragma unroll                       // T2 read -> R: reg p = kw
            for (int p = 0; p < 16; p++)
                v[p] = __half22float2(LTH[a2r + 8 * BR4(p)]);
            __syncthreads();
            pass_A_inv(v, c, fA, tA);            // iFw: natural w = c+8i
            #pragma unroll                       // * patch(slice s)
            for (int i = 0; i < 16; i++) {
                int w  = c + 8 * i;
                int oi = (s * OBJW + Y0 + g) * OBJW + X0 + w;
                float2 ob = make_float2(obj_re[oi], obj_im[oi]);
                v[i] = cmul(v[i], ob);
            }
        }

        // final FFT2: Fw, T1, Fh(pass_B), |.|^2 RMW into out
        pass_A_fwd(v, c, fA, tA);
        #pragma unroll
        for (int p = 0; p < 16; p++) {
            int kw = BR4(p) + 16 * rc;
            LTH[kw * LSTR + a1w] = __float22half2_rn(v[p]);
        }
        __syncthreads();
        #pragma unroll
        for (int i = 0; i < 16; i++)
            v[i] = __half22float2(LTH[a1r + 8 * i]);
        pass_B_fwd(v, c, fA, tB);
        // fftshift: (kh,kw)->(kh^64,kw^64); kh=br3(c)+8BR4(p), kw=g.
        // Same thread owns the same slots every mode -> plain RMW, no race.
        #pragma unroll
        for (int p = 0; p < 16; p++) {
            int kh = BR3(c) + 8 * BR4(p);
            long long oidx = base + (long long)(((kh ^ 64) << 7) + (g ^ 64));
            float val = fmaf(v[p].x, v[p].x, v[p].y * v[p].y);
            if (m > 0) val += out[oidx];
            out[oidx] = val;
        }
    }
}

extern "C" void kernel_launch(void* const* d_in, const int* in_sizes, int n_in,
                              void* d_out, int out_size, void* d_ws, size_t ws_size,
                              hipStream_t stream) {
    const float* probe_re = (const float*)d_in[0];
    const float* probe_im = (const float*)d_in[1];
    const float* obj_re   = (const float*)d_in[2];
    const float* obj_im   = (const float*)d_in[3];
    const int*   pos      = (const int*)d_in[4];
    float* out = (float*)d_out;

    const int N = out_size / NPIX;   // 512 positions
    multislice_kernel<<<dim3(N), dim3(NT), 0, stream>>>(
        probe_re, probe_im, obj_re, obj_im, pos, out);
}

// Round 2
// 1224.710 us; speedup vs baseline: 1.0790x; 1.0790x over previous
//
#include <hip/hip_runtime.h>
#include <hip/hip_fp16.h>
#include <math.h>

#define NT      1024
#define NPIX    16384
#define NSLICES 8
#define NMODES  4
#define OBJW    512
#define LSTR    136        // padded major stride (half2 units): 136%32=8

typedef float v2f __attribute__((ext_vector_type(2)));

// ---- packed fp32 complex primitives (VOP3P) --------------------------------
__device__ __forceinline__ v2f pk_add(v2f a, v2f b) {
    v2f d; asm("v_pk_add_f32 %0, %1, %2" : "=v"(d) : "v"(a), "v"(b)); return d;
}
__device__ __forceinline__ v2f pk_sub(v2f a, v2f b) {
    v2f d; asm("v_pk_add_f32 %0, %1, %2 neg_lo:[0,1] neg_hi:[0,1]"
               : "=v"(d) : "v"(a), "v"(b)); return d;
}
__device__ __forceinline__ v2f pk_fma(v2f a, v2f b, v2f c) {
    v2f d; asm("v_pk_fma_f32 %0, %1, %2, %3" : "=v"(d) : "v"(a), "v"(b), "v"(c)); return d;
}
// d = a*b (complex):  t=(ax*bx, ay*bx);  d=(t.x - ay*by, t.y + ax*by)
__device__ __forceinline__ v2f pk_cmul(v2f a, v2f b) {
    v2f t, d;
    asm("v_pk_mul_f32 %0, %1, %2 op_sel:[0,0] op_sel_hi:[1,0]"
        : "=v"(t) : "v"(a), "v"(b));
    asm("v_pk_fma_f32 %0, %1, %2, %3 op_sel:[1,1,0] op_sel_hi:[0,1,1] neg_lo:[1,0,0]"
        : "=v"(d) : "v"(a), "v"(b), "v"(t));
    return d;
}
// d = a*conj(b):  t=(ax*bx, ay*bx);  d=(t.x + ay*by, t.y - ax*by)
__device__ __forceinline__ v2f pk_cmulc(v2f a, v2f b) {
    v2f t, d;
    asm("v_pk_mul_f32 %0, %1, %2 op_sel:[0,0] op_sel_hi:[1,0]"
        : "=v"(t) : "v"(a), "v"(b));
    asm("v_pk_fma_f32 %0, %1, %2, %3 op_sel:[1,1,0] op_sel_hi:[0,1,1] neg_hi:[1,0,0]"
        : "=v"(d) : "v"(a), "v"(b), "v"(t));
    return d;
}
__device__ __forceinline__ v2f pk_mnegi(v2f a) { return (v2f){a.y, -a.x}; }  // a * -i
__device__ __forceinline__ v2f pk_mposi(v2f a) { return (v2f){-a.y, a.x}; }  // a * +i

// 4-bit reversal (constexpr -> folds to literals in unrolled loops)
__host__ __device__ constexpr int BR4(int p) {
    return ((p & 1) << 3) | ((p & 2) << 1) | ((p & 4) >> 1) | ((p & 8) >> 3);
}
__host__ __device__ constexpr int BR3(int c) {
    return ((c & 1) << 2) | (c & 2) | ((c & 4) >> 2);
}

// ---- lane exchange primitives ---------------------------------------------
// xor1/xor2 stay inside a quad -> DPP quad_perm (full-rate VALU, no LDS pipe).
// xor4 -> ds_swizzle bit-mode.
__device__ __forceinline__ float xor1f(float x) {
    int i = __float_as_int(x);
    return __int_as_float(__builtin_amdgcn_update_dpp(i, i, 0xB1, 0xF, 0xF, false));
}
__device__ __forceinline__ float xor2f(float x) {
    int i = __float_as_int(x);
    return __int_as_float(__builtin_amdgcn_update_dpp(i, i, 0x4E, 0xF, 0xF, false));
}
__device__ __forceinline__ float xor4f(float x) {
    return __int_as_float(__builtin_amdgcn_ds_swizzle(__float_as_int(x), 0x101F));
}

// cross-8 stage-A twiddle fA(c) = (c<4) ? 1 : W8^(c-4)
__device__ __constant__ float FA_RE[8] = {1,1,1,1, 1.0f,  0.707106781f,  0.0f, -0.707106781f};
__device__ __constant__ float FA_IM[8] = {0,0,0,0, 0.0f, -0.707106781f, -1.0f, -0.707106781f};

// ---- local 16-point FFT in registers (packed) ------------------------------
// W[k] = (cos, sin) of 2*pi*k/16
__device__ __forceinline__ void fft16_fwd(v2f v[16], const v2f* W) {
    #pragma unroll
    for (int s = 8; s >= 1; s >>= 1) {
        #pragma unroll
        for (int q = 0; q < 16; q += 2 * s) {
            #pragma unroll
            for (int j = 0; j < s; j++) {
                const int tw = j * (8 / s);
                v2f u = v[q + j], w = v[q + j + s];
                v[q + j] = pk_add(u, w);
                v2f d = pk_sub(u, w);
                v[q + j + s] = (tw == 0) ? d
                             : (tw == 4) ? pk_mnegi(d)
                                         : pk_cmulc(d, W[tw]);
            }
        }
    }
}
__device__ __forceinline__ void fft16_inv(v2f v[16], const v2f* W) {
    #pragma unroll
    for (int s = 1; s <= 8; s <<= 1) {
        #pragma unroll
        for (int q = 0; q < 16; q += 2 * s) {
            #pragma unroll
            for (int j = 0; j < s; j++) {
                const int tw = j * (8 / s);
                v2f u = v[q + j], w = v[q + j + s];
                v2f tv = (tw == 0) ? w
                       : (tw == 4) ? pk_mposi(w)
                                   : pk_cmul(w, W[tw]);
                v[q + j]     = pk_add(u, tv);
                v[q + j + s] = pk_sub(u, tv);
            }
        }
    }
}

// ---- cross-thread DFT8 over sub-index c (xor 4,2,1) ------------------------
// fwd: natural in, output at thread br3(c). inv: br3-in, natural out (unnorm).
// sXp = (+-1,+-1) per-lane sign pairs; rrf = rot3 ? (0,-1) : (1,0).
__device__ __forceinline__ void cross8_fwd(v2f v[16], v2f sAp, v2f sBp, v2f sCp,
                                           v2f fA, v2f rrf) {
    #pragma unroll
    for (int p = 0; p < 16; p++) {
        v2f o;
        o.x = xor4f(v[p].x); o.y = xor4f(v[p].y);
        v2f a = pk_fma(sAp, v[p], o);
        v2f b = pk_cmul(a, fA);
        o.x = xor2f(b.x); o.y = xor2f(b.y);
        v2f n = pk_fma(sBp, b, o);
        v2f r = pk_cmul(n, rrf);
        o.x = xor1f(r.x); o.y = xor1f(r.y);
        v[p] = pk_fma(sCp, r, o);
    }
}
__device__ __forceinline__ void cross8_inv(v2f v[16], v2f sAp, v2f sBp, v2f sCp,
                                           v2f fA, v2f rrf) {
    #pragma unroll
    for (int p = 0; p < 16; p++) {
        v2f o;
        o.x = xor1f(v[p].x); o.y = xor1f(v[p].y);
        v2f n = pk_fma(sCp, v[p], o);
        v2f r = pk_cmulc(n, rrf);
        o.x = xor2f(r.x); o.y = xor2f(r.y);
        v2f b = pk_fma(sBp, r, o);
        v2f a = pk_cmulc(b, fA);
        o.x = xor4f(a.x); o.y = xor4f(a.y);
        v[p] = pk_fma(sAp, a, o);
    }
}

// ---- pass A (local-first): input reg i = elem c+8i; out reg p = BR4(p)+16rc
__device__ __forceinline__ void pass_A_fwd(v2f v[16], int c, v2f sAp, v2f sBp,
                                           v2f sCp, v2f fA, v2f rrf,
                                           const v2f* W, const v2f* tA) {
    fft16_fwd(v, W);
    #pragma unroll
    for (int p = 0; p < 16; p++) v[p] = pk_cmul(v[p], tA[8 * p + c]);
    cross8_fwd(v, sAp, sBp, sCp, fA, rrf);
}
__device__ __forceinline__ void pass_A_inv(v2f v[16], int c, v2f sAp, v2f sBp,
                                           v2f sCp, v2f fA, v2f rrf,
                                           const v2f* W, const v2f* tA) {
    cross8_inv(v, sAp, sBp, sCp, fA, rrf);
    #pragma unroll
    for (int p = 0; p < 16; p++) v[p] = pk_cmulc(v[p], tA[8 * p + c]);
    fft16_inv(v, W);
}

// ---- pass B (cross-first): input reg i = elem i+16c
__device__ __forceinline__ void pass_B_fwd(v2f v[16], int c, v2f sAp, v2f sBp,
                                           v2f sCp, v2f fA, v2f rrf,
                                           const v2f* W, const v2f* tB) {
    cross8_fwd(v, sAp, sBp, sCp, fA, rrf);
    #pragma unroll
    for (int i = 0; i < 16; i++) v[i] = pk_cmul(v[i], tB[8 * i + c]);
    fft16_fwd(v, W);
}
__device__ __forceinline__ void pass_B_inv(v2f v[16], int c, v2f sAp, v2f sBp,
                                           v2f sCp, v2f fA, v2f rrf,
                                           const v2f* W, const v2f* tB) {
    fft16_inv(v, W);
    #pragma unroll
    for (int i = 0; i < 16; i++) v[i] = pk_cmulc(v[i], tB[8 * i + c]);
    cross8_inv(v, sAp, sBp, sCp, fA, rrf);
}

// ---- conversions -----------------------------------------------------------
__device__ __forceinline__ __half2 toh2(v2f a) {
    return __float22half2_rn(make_float2(a.x, a.y));
}
__device__ __forceinline__ v2f frh2(__half2 h) {
    float2 f = __half22float2(h);
    return (v2f){f.x, f.y};
}

// ---- main kernel: one block per position; 1 WG/CU (72.7KB LDS) -------------
__global__ void
__attribute__((amdgpu_flat_work_group_size(1024, 1024)))
multislice_kernel(const float* __restrict__ probe_re,
                  const float* __restrict__ probe_im,
                  const float* __restrict__ obj_re,
                  const float* __restrict__ obj_im,
                  const int*   __restrict__ positions,
                  float*       __restrict__ out)
{
    __shared__ __half2 LTH[128 * LSTR];   // 69632 B transpose buffer (fp16)
    __shared__ v2f     tA[128];           // pass-A twiddle [8p+c]
    __shared__ v2f     tB[128];           // pass-B twiddle [8i+c]
    __shared__ v2f     pytp[128];         // prop y-factor/16384, kh=br3(c)+8BR4(p)

    const int t  = threadIdx.x;
    const int g  = t >> 3;                      // row (R) / col (C) index
    const int c  = t & 7;
    const int rc = BR3(c);
    const int gh = g >> 4;                      // sigma(g)
    const int rho_g = ((g & 15) << 3) | gh;     // rho(g)
    const int n  = blockIdx.x;
    const int Y0 = positions[2 * n];
    const int X0 = positions[2 * n + 1];

    if (t < 128) {
        int p_ = t >> 3, c_ = t & 7;
        float angA = -2.0f * 3.14159265358979323846f
                     * (float)(c_ * BR4(p_)) / 128.0f;
        float s, cc; __sincosf(angA, &s, &cc);
        tA[t] = (v2f){cc, s};
        float angB = -2.0f * 3.14159265358979323846f
                     * (float)(p_ * BR3(c_)) / 128.0f;
        __sincosf(angB, &s, &cc);
        tB[t] = (v2f){cc, s};
        int kh = BR3(c_) + 8 * BR4(p_);
        float fy = (float)(kh < 64 ? kh : kh - 128) * (1.0f / 25.6f);
        float ph = -0.15707963267948966f * fy * fy;
        float ps, pcs; __sincosf(ph, &ps, &pcs);
        pytp[t] = (v2f){pcs * (1.0f / 16384.0f), ps * (1.0f / 16384.0f)};
    }

    // per-thread constants for the cross-8 stages
    const float sA = (c < 4) ? 1.0f : -1.0f;
    const float sB = (c & 2) ? -1.0f : 1.0f;
    const float sC = (c & 1) ? -1.0f : 1.0f;
    const v2f sAp = {sA, sA}, sBp = {sB, sB}, sCp = {sC, sC};
    const v2f fA  = {FA_RE[c], FA_IM[c]};
    const v2f rrf = ((c & 3) == 3) ? (v2f){0.0f, -1.0f} : (v2f){1.0f, 0.0f};

    // W16 twiddle pairs (compile-time constants -> hoisted into registers)
    const v2f W[8] = {
        { 1.0f,         0.0f        },
        { 0.923879533f, 0.382683432f},
        { 0.707106781f, 0.707106781f},
        { 0.382683432f, 0.923879533f},
        { 0.0f,         1.0f        },
        {-0.382683432f, 0.923879533f},
        {-0.707106781f, 0.707106781f},
        {-0.923879533f, 0.382683432f},
    };

    float fx = (float)(g < 64 ? g : g - 128) * (1.0f / 25.6f);
    float phx = -0.15707963267948966f * fx * fx;
    float pxs, pxc; __sincosf(phx, &pxs, &pxc);
    const v2f px = {pxc, pxs};
    __syncthreads();

    const long long base = (long long)n * NPIX;
    // precomputed transpose address bases
    const int a1w = rho_g ^ rc;                    // T1-write minor
    const int a1r = g * LSTR + (c ^ gh);           // + 8i
    const int a2w = rho_g ^ c;                     // T2-write minor
    const int a2r = g * LSTR + (rc ^ gh);          // + 8*BR4(p)

    v2f v[16];

    for (int m = 0; m < NMODES; m++) {
        __syncthreads();   // protect LTH reuse across modes
        #pragma unroll
        for (int i = 0; i < 16; i++) {           // ex = probe[m]*patch(slice0)
            int w  = c + 8 * i;
            int pi = m * NPIX + g * 128 + w;
            v2f pr = {probe_re[pi], probe_im[pi]};
            int oi = (Y0 + g) * OBJW + X0 + w;
            v2f ob = {obj_re[oi], obj_im[oi]};
            v[i] = pk_cmul(pr, ob);
        }

        for (int s = 1; s < NSLICES; s++) {
            pass_A_fwd(v, c, sAp, sBp, sCp, fA, rrf, W, tA);
            #pragma unroll                       // T1 write [kw][r=g]
            for (int p = 0; p < 16; p++) {
                int kw = BR4(p) + 16 * rc;
                LTH[kw * LSTR + a1w] = toh2(v[p]);
            }
            __syncthreads();
            #pragma unroll                       // T1 read -> C: reg i = row i+16c
            for (int i = 0; i < 16; i++)
                v[i] = frh2(LTH[a1r + 8 * i]);
            __syncthreads();
            pass_B_fwd(v, c, sAp, sBp, sCp, fA, rrf, W, tB);
            #pragma unroll                       // * prop
            for (int p = 0; p < 16; p++) {
                v2f pp = pk_cmul(pytp[8 * p + c], px);
                v[p] = pk_cmul(v[p], pp);
            }
            pass_B_inv(v, c, sAp, sBp, sCp, fA, rrf, W, tB);
            #pragma unroll                       // T2 write [r=i+16c][g]
            for (int i = 0; i < 16; i++)
                LTH[(i + 16 * c) * LSTR + a2w] = toh2(v[i]);
            __syncthreads();
            #pragma unroll                       // T2 read -> R: reg p = kw
            for (int p = 0; p < 16; p++)
                v[p] = frh2(LTH[a2r + 8 * BR4(p)]);
            __syncthreads();
            pass_A_inv(v, c, sAp, sBp, sCp, fA, rrf, W, tA);
            #pragma unroll                       // * patch(slice s)
            for (int i = 0; i < 16; i++) {
                int w  = c + 8 * i;
                int oi = (s * OBJW + Y0 + g) * OBJW + X0 + w;
                v2f ob = {obj_re[oi], obj_im[oi]};
                v[i] = pk_cmul(v[i], ob);
            }
        }

        // final FFT2: Fw, T1, Fh(pass_B), |.|^2 RMW into out
        pass_A_fwd(v, c, sAp, sBp, sCp, fA, rrf, W, tA);
        #pragma unroll
        for (int p = 0; p < 16; p++) {
            int kw = BR4(p) + 16 * rc;
            LTH[kw * LSTR + a1w] = toh2(v[p]);
        }
        __syncthreads();
        #pragma unroll
        for (int i = 0; i < 16; i++)
            v[i] = frh2(LTH[a1r + 8 * i]);
        pass_B_fwd(v, c, sAp, sBp, sCp, fA, rrf, W, tB);
        // fftshift: (kh,kw)->(kh^64,kw^64); kh=br3(c)+8BR4(p), kw=g.
        #pragma unroll
        for (int p = 0; p < 16; p++) {
            int kh = BR3(c) + 8 * BR4(p);
            long long oidx = base + (long long)(((kh ^ 64) << 7) + (g ^ 64));
            float val = fmaf(v[p].x, v[p].x, v[p].y * v[p].y);
            if (m > 0) val += out[oidx];
            out[oidx] = val;
        }
    }
}

extern "C" void kernel_launch(void* const* d_in, const int* in_sizes, int n_in,
                              void* d_out, int out_size, void* d_ws, size_t ws_size,
                              hipStream_t stream) {
    const float* probe_re = (const float*)d_in[0];
    const float* probe_im = (const float*)d_in[1];
    const float* obj_re   = (const float*)d_in[2];
    const float* obj_im   = (const float*)d_in[3];
    const int*   pos      = (const int*)d_in[4];
    float* out = (float*)d_out;

    const int N = out_size / NPIX;   // 512 positions
    multislice_kernel<<<dim3(N), dim3(NT), 0, stream>>>(
        probe_re, probe_im, obj_re, obj_im, pos, out);
}